// Round 2
// baseline (291.914 us; speedup 1.0000x reference)
//
#include <hip/hip_runtime.h>

#define IN_D  128
#define HID_D 128
#define OUT_D 64
#define CAP   32          // fixed neighbor capacity (Poisson(6): P(deg>32)~1e-15)

static inline size_t align256(size_t x) { return (x + 255) & ~(size_t)255; }

typedef short bf8_t  __attribute__((ext_vector_type(8)));   // 8 bf16 (4 VGPRs)
typedef float f32x4  __attribute__((ext_vector_type(4)));   // 4 fp32 acc

union BF8 { bf8_t v; unsigned short u[8]; uint4 q; };

__device__ __forceinline__ unsigned short f2bf(float f) {   // RNE fp32->bf16
    unsigned int u = __float_as_uint(f);
    u += 0x7FFF + ((u >> 16) & 1);
    return (unsigned short)(u >> 16);
}
__device__ __forceinline__ float bflo(unsigned int u) { return __uint_as_float(u << 16); }
__device__ __forceinline__ float bfhi(unsigned int u) { return __uint_as_float(u & 0xFFFF0000u); }

__device__ __forceinline__ void acc8(float* a, uint4 v) {
    a[0] += bflo(v.x); a[1] += bfhi(v.x);
    a[2] += bflo(v.y); a[3] += bfhi(v.y);
    a[4] += bflo(v.z); a[5] += bfhi(v.z);
    a[6] += bflo(v.w); a[7] += bfhi(v.w);
}
__device__ __forceinline__ void accm8(float* a, uint4 v, float msk) {  // masked
    a[0] = fmaf(msk, bflo(v.x), a[0]); a[1] = fmaf(msk, bfhi(v.x), a[1]);
    a[2] = fmaf(msk, bflo(v.y), a[2]); a[3] = fmaf(msk, bfhi(v.y), a[3]);
    a[4] = fmaf(msk, bflo(v.z), a[4]); a[5] = fmaf(msk, bfhi(v.z), a[5]);
    a[6] = fmaf(msk, bflo(v.w), a[6]); a[7] = fmaf(msk, bfhi(v.w), a[7]);
}

// ---- bucket-CSR placement (hist+place in one) + W pre-swizzle --------------
__global__ __launch_bounds__(256) void place_prep(
    const int* __restrict__ src, const int* __restrict__ dst,
    int* __restrict__ deg, int* __restrict__ srcs,
    const float* __restrict__ W1, const float* __restrict__ W2,
    unsigned short* __restrict__ Wb1, unsigned short* __restrict__ Wb2, int E)
{
    int i = blockIdx.x * 256 + threadIdx.x;
    if (i < 6144) {                       // W prep (blocks 0..23)
        if (i < 4096) {                   // W1: kk(4) x t(8) x lane(64)
            int L = i & 63, t = (i >> 6) & 7, kk = i >> 9;
            int kbase = kk * 32 + (L >> 4) * 8;
            int col = t * 16 + (L & 15);
            unsigned short* o = Wb1 + (size_t)i * 8;
#pragma unroll
            for (int j = 0; j < 8; ++j) o[j] = f2bf(W1[(size_t)(kbase + j) * HID_D + col]);
        } else {                          // W2: kk(4) x t(4) x lane(64)
            int r = i - 4096;
            int L = r & 63, t = (r >> 6) & 3, kk = r >> 8;
            int kbase = kk * 32 + (L >> 4) * 8;
            int col = t * 16 + (L & 15);
            unsigned short* o = Wb2 + (size_t)r * 8;
#pragma unroll
            for (int j = 0; j < 8; ++j) o[j] = f2bf(W2[(size_t)(kbase + j) * OUT_D + col]);
        }
    }
    if (i < E) {
        int d = dst[i];
        int pos = atomicAdd(&deg[d], 1);
        if (pos < CAP) srcs[(size_t)d * CAP + pos] = src[i];
    }
}

// ---- GEMM1 (MFMA): h[n,128]bf16 = rsqrt(deg+1) * (x[n,128]f32 @ W1) --------
__global__ __launch_bounds__(256) void gemm1(const float* __restrict__ x,
                                             const unsigned short* __restrict__ Wb,
                                             const int* __restrict__ deg,
                                             unsigned short* __restrict__ h, int n) {
    __shared__ __align__(16) unsigned short Ws[4 * 8 * 64 * 8];   // 32 KB
    {
        const uint4* g = (const uint4*)Wb;
        uint4* l = (uint4*)Ws;
        for (int i = threadIdx.x; i < 2048; i += 256) l[i] = g[i];
    }
    const int wave = threadIdx.x >> 6, lane = threadIdx.x & 63;
    const int wrow0 = blockIdx.x * 64 + wave * 16;
    const int mrow = min(wrow0 + (lane & 15), n - 1);
    const float* xr = x + (size_t)mrow * IN_D + ((lane >> 4) * 8);

    BF8 af[4];
#pragma unroll
    for (int kk = 0; kk < 4; ++kk) {
        float4 p  = *(const float4*)(xr + kk * 32);
        float4 q2 = *(const float4*)(xr + kk * 32 + 4);
        af[kk].u[0] = f2bf(p.x);  af[kk].u[1] = f2bf(p.y);
        af[kk].u[2] = f2bf(p.z);  af[kk].u[3] = f2bf(p.w);
        af[kk].u[4] = f2bf(q2.x); af[kk].u[5] = f2bf(q2.y);
        af[kk].u[6] = f2bf(q2.z); af[kk].u[7] = f2bf(q2.w);
    }
    __syncthreads();

    f32x4 acc[8];
#pragma unroll
    for (int t = 0; t < 8; ++t) acc[t] = (f32x4){0.f, 0.f, 0.f, 0.f};
    const bf8_t* B = (const bf8_t*)Ws;
#pragma unroll
    for (int kk = 0; kk < 4; ++kk) {
#pragma unroll
        for (int t = 0; t < 8; ++t) {
            bf8_t b = B[(kk * 8 + t) * 64 + lane];
            acc[t] = __builtin_amdgcn_mfma_f32_16x16x32_bf16(af[kk].v, b, acc[t], 0, 0, 0);
        }
    }
    const int q = lane >> 4, cbase = lane & 15;
    int rr[4]; float di[4];
#pragma unroll
    for (int r = 0; r < 4; ++r) {
        rr[r] = wrow0 + q * 4 + r;
        di[r] = rsqrtf((float)(deg[min(rr[r], n - 1)] + 1));
    }
#pragma unroll
    for (int t = 0; t < 8; ++t) {
        int col = t * 16 + cbase;
#pragma unroll
        for (int r = 0; r < 4; ++r)
            if (rr[r] < n) h[(size_t)rr[r] * HID_D + col] = f2bf(acc[t][r] * di[r]);
    }
}

// ---- FUSED layer-1 aggregate + layer-2 GEMM --------------------------------
// Phase A: gather 64 nodes (16 lanes/node, 4 passes) -> relu(bias(dinv*sum))
//          -> bf16 tile in LDS (row stride 136 ushorts)
// Phase B: MFMA the 64x128 LDS tile against W2 read DIRECT FROM GLOBAL (L2-hot,
//          16 KB) -- no W2 LDS stage, so LDS = 17 KB.
// __launch_bounds__(256, 8): force VGPR<=64 -- at 68 VGPRs we sit just past the
// 64-reg occupancy cliff (waves/SIMD halve 8->4, measured Occupancy=22.7%).
// This kernel is latency-bound (VALUBusy 30%, Mfma 1.3%, HBM 28%), so resident
// waves are the whole game.
#define AGG_STRIDE 136
__global__ __launch_bounds__(256, 8) void agg_gemm2(
    const unsigned short* __restrict__ hp, const int* __restrict__ srcs,
    const int* __restrict__ deg, const float* __restrict__ b1,
    const unsigned short* __restrict__ Wb2,
    unsigned short* __restrict__ g2, int n)
{
    __shared__ __align__(16) unsigned short aggs[64 * AGG_STRIDE]; // 17 KB
    const int tid = threadIdx.x;
    const int base = blockIdx.x * 64;
    const int m = tid & 15;

    // ---- phase A: gather ----
#pragma unroll 1
    for (int pass = 0; pass < 4; ++pass) {
        int nl   = pass * 16 + (tid >> 4);
        int node = min(base + nl, n - 1);
        int dv    = deg[node];
        int k     = min(dv, CAP);
        int start = node * CAP;
        const uint4* tab = (const uint4*)hp + m;    // row stride = 16 uint4

        uint4 u = tab[(size_t)node * 16];           // self-loop term
        float a[8] = {0, 0, 0, 0, 0, 0, 0, 0};
        acc8(a, u);
        for (int j0 = 0; j0 < k; j0 += 8) {
            int is[8];
#pragma unroll
            for (int t = 0; t < 8; ++t) is[t] = srcs[start + min(j0 + t, k - 1)];
            uint4 v[8];
#pragma unroll
            for (int t = 0; t < 8; ++t) v[t] = tab[(size_t)is[t] * 16];
#pragma unroll
            for (int t = 0; t < 8; ++t)
                accm8(a, v[t], (j0 + t < k) ? 1.0f : 0.0f);
        }
        float di = rsqrtf((float)(dv + 1));
        const float* bb = b1 + m * 8;
        uint4 w;
        float o0, o1;
        o0 = fmaxf(a[0] * di + bb[0], 0.f);
        o1 = fmaxf(a[1] * di + bb[1], 0.f);
        w.x = (unsigned int)f2bf(o0) | ((unsigned int)f2bf(o1) << 16);
        o0 = fmaxf(a[2] * di + bb[2], 0.f);
        o1 = fmaxf(a[3] * di + bb[3], 0.f);
        w.y = (unsigned int)f2bf(o0) | ((unsigned int)f2bf(o1) << 16);
        o0 = fmaxf(a[4] * di + bb[4], 0.f);
        o1 = fmaxf(a[5] * di + bb[5], 0.f);
        w.z = (unsigned int)f2bf(o0) | ((unsigned int)f2bf(o1) << 16);
        o0 = fmaxf(a[6] * di + bb[6], 0.f);
        o1 = fmaxf(a[7] * di + bb[7], 0.f);
        w.w = (unsigned int)f2bf(o0) | ((unsigned int)f2bf(o1) << 16);
        *(uint4*)&aggs[nl * AGG_STRIDE + m * 8] = w;
    }
    __syncthreads();

    // ---- phase B: MFMA 64x128 tile @ W2 (B-frags from global/L2) -> 64x64 ---
    const int wave = tid >> 6, lane = tid & 63;
    const int qd = lane >> 4;
    const int arow = wave * 16 + (lane & 15);

    f32x4 acc[4];
#pragma unroll
    for (int t = 0; t < 4; ++t) acc[t] = (f32x4){0.f, 0.f, 0.f, 0.f};
    const bf8_t* B = (const bf8_t*)Wb2;
#pragma unroll
    for (int kk = 0; kk < 4; ++kk) {
        // load A-fragment per-kk (4 VGPRs live) instead of all 16 upfront --
        // keeps peak pressure under the 64-VGPR budget
        BF8 afk;
        afk.q = *(const uint4*)&aggs[arow * AGG_STRIDE + kk * 32 + qd * 8];
#pragma unroll
        for (int t = 0; t < 4; ++t) {
            bf8_t b = B[(kk * 4 + t) * 64 + lane];
            acc[t] = __builtin_amdgcn_mfma_f32_16x16x32_bf16(afk.v, b, acc[t], 0, 0, 0);
        }
    }
    const int cbase = lane & 15;
    int rr[4]; float di[4];
#pragma unroll
    for (int r = 0; r < 4; ++r) {
        rr[r] = base + wave * 16 + qd * 4 + r;
        di[r] = rsqrtf((float)(deg[min(rr[r], n - 1)] + 1));
    }
#pragma unroll
    for (int t = 0; t < 4; ++t) {
        int col = t * 16 + cbase;
#pragma unroll
        for (int r = 0; r < 4; ++r)
            if (rr[r] < n) g2[(size_t)rr[r] * OUT_D + col] = f2bf(acc[t][r] * di[r]);
    }
}

// ---- gather layer 2: 8 nodes/wave (8 lanes each), 8-deep load batches ------
// Same latency-bound profile as agg_gemm2 phase A -> same occupancy forcing.
__global__ __launch_bounds__(256, 8) void gather64(const unsigned short* __restrict__ gp,
                                                   const int* __restrict__ srcs,
                                                   const int* __restrict__ deg,
                                                   const float* __restrict__ b,
                                                   float* __restrict__ out, int n) {
    int idx  = blockIdx.x * 256 + threadIdx.x;
    int node = idx >> 3;            // one node per 8-lane group
    int m    = idx & 7;             // 16B chunk index within 128B row
    if (node >= n) return;
    int dv    = deg[node];
    int k     = min(dv, CAP);
    int start = node * CAP;
    const uint4* tab = (const uint4*)gp + m;    // row stride = 8 uint4

    uint4 u = tab[(size_t)node * 8];            // self-loop term
    float a[8] = {0, 0, 0, 0, 0, 0, 0, 0};
    acc8(a, u);
    for (int j0 = 0; j0 < k; j0 += 8) {
        int is[8];
#pragma unroll
        for (int t = 0; t < 8; ++t) is[t] = srcs[start + min(j0 + t, k - 1)];
        uint4 v[8];
#pragma unroll
        for (int t = 0; t < 8; ++t) v[t] = tab[(size_t)is[t] * 8];
#pragma unroll
        for (int t = 0; t < 8; ++t)
            accm8(a, v[t], (j0 + t < k) ? 1.0f : 0.0f);
    }
    float di = rsqrtf((float)(dv + 1));
    const float* bb = b + m * 8;
    float4 w0, w1;
    w0.x = a[0] * di + bb[0];
    w0.y = a[1] * di + bb[1];
    w0.z = a[2] * di + bb[2];
    w0.w = a[3] * di + bb[3];
    w1.x = a[4] * di + bb[4];
    w1.y = a[5] * di + bb[5];
    w1.z = a[6] * di + bb[6];
    w1.w = a[7] * di + bb[7];
    float* o = out + (size_t)node * OUT_D + m * 8;
    *(float4*)o = w0;
    *(float4*)(o + 4) = w1;
}

extern "C" void kernel_launch(void* const* d_in, const int* in_sizes, int n_in,
                              void* d_out, int out_size, void* d_ws, size_t ws_size,
                              hipStream_t stream) {
    const float* x  = (const float*)d_in[0];
    const int*   ei = (const int*)d_in[1];
    const float* W1 = (const float*)d_in[2];
    const float* b1 = (const float*)d_in[3];
    const float* W2 = (const float*)d_in[4];
    const float* b2 = (const float*)d_in[5];
    float* out = (float*)d_out;

    const int n = in_sizes[0] / IN_D;   // 100000
    const int E = in_sizes[1] / 2;      // 600000
    const int* src = ei;
    const int* dst = ei + E;

    // workspace layout (~52 MB)
    char* ws = (char*)d_ws;
    size_t off = 0;
    int* deg  = (int*)(ws + off); off += align256((size_t)n * sizeof(int));
    int* srcs = (int*)(ws + off); off += align256((size_t)n * CAP * sizeof(int));
    unsigned short* Wb1 = (unsigned short*)(ws + off); off += align256(4096 * 8 * sizeof(unsigned short));
    unsigned short* Wb2 = (unsigned short*)(ws + off); off += align256(2048 * 8 * sizeof(unsigned short));
    unsigned short* h1  = (unsigned short*)(ws + off); off += align256((size_t)n * HID_D * sizeof(unsigned short));
    unsigned short* g2  = (unsigned short*)(ws + off); off += align256((size_t)n * OUT_D * sizeof(unsigned short));

    // 1) zero degree counters
    hipMemsetAsync(deg, 0, (size_t)n * sizeof(int), stream);
    // 2) bucket-CSR placement + weight pre-swizzle
    place_prep<<<(E + 255) / 256, 256, 0, stream>>>(src, dst, deg, srcs,
                                                    W1, W2, Wb1, Wb2, E);
    // 3) layer 1 transform
    gemm1<<<(n + 63) / 64, 256, 0, stream>>>(x, Wb1, deg, h1, n);
    // 4) fused layer-1 aggregate + layer-2 transform
    agg_gemm2<<<(n + 63) / 64, 256, 0, stream>>>(h1, srcs, deg, b1, Wb2, g2, n);
    // 5) layer 2 aggregate + bias -> out (fp32)
    gather64<<<(n + 31) / 32, 256, 0, stream>>>(g2, srcs, deg, b2, out, n);
}

// Round 3
// 194.270 us; speedup vs baseline: 1.5026x; 1.5026x over previous
//
#include <hip/hip_runtime.h>

#define IN_D  128
#define HID_D 128
#define OUT_D 64
#define CAP   32          // fixed neighbor capacity (Poisson(6): P(deg>32)~1e-15)

static inline size_t align256(size_t x) { return (x + 255) & ~(size_t)255; }

typedef short bf8_t  __attribute__((ext_vector_type(8)));   // 8 bf16 (4 VGPRs)
typedef float f32x4  __attribute__((ext_vector_type(4)));   // 4 fp32 acc

union BF8 { bf8_t v; unsigned short u[8]; uint4 q; };

__device__ __forceinline__ unsigned short f2bf(float f) {   // RNE fp32->bf16
    unsigned int u = __float_as_uint(f);
    u += 0x7FFF + ((u >> 16) & 1);
    return (unsigned short)(u >> 16);
}
__device__ __forceinline__ float bflo(unsigned int u) { return __uint_as_float(u << 16); }
__device__ __forceinline__ float bfhi(unsigned int u) { return __uint_as_float(u & 0xFFFF0000u); }

__device__ __forceinline__ void acc8(float* a, uint4 v) {
    a[0] += bflo(v.x); a[1] += bfhi(v.x);
    a[2] += bflo(v.y); a[3] += bfhi(v.y);
    a[4] += bflo(v.z); a[5] += bfhi(v.z);
    a[6] += bflo(v.w); a[7] += bfhi(v.w);
}
__device__ __forceinline__ void accm8(float* a, uint4 v, float msk) {  // masked
    a[0] = fmaf(msk, bflo(v.x), a[0]); a[1] = fmaf(msk, bfhi(v.x), a[1]);
    a[2] = fmaf(msk, bflo(v.y), a[2]); a[3] = fmaf(msk, bfhi(v.y), a[3]);
    a[4] = fmaf(msk, bflo(v.z), a[4]); a[5] = fmaf(msk, bfhi(v.z), a[5]);
    a[6] = fmaf(msk, bflo(v.w), a[6]); a[7] = fmaf(msk, bfhi(v.w), a[7]);
}

// ---- bucket-CSR placement (hist+place in one) + W pre-swizzle --------------
__global__ __launch_bounds__(256) void place_prep(
    const int* __restrict__ src, const int* __restrict__ dst,
    int* __restrict__ deg, int* __restrict__ srcs,
    const float* __restrict__ W1, const float* __restrict__ W2,
    unsigned short* __restrict__ Wb1, unsigned short* __restrict__ Wb2, int E)
{
    int i = blockIdx.x * 256 + threadIdx.x;
    if (i < 6144) {                       // W prep (blocks 0..23)
        if (i < 4096) {                   // W1: kk(4) x t(8) x lane(64)
            int L = i & 63, t = (i >> 6) & 7, kk = i >> 9;
            int kbase = kk * 32 + (L >> 4) * 8;
            int col = t * 16 + (L & 15);
            unsigned short* o = Wb1 + (size_t)i * 8;
#pragma unroll
            for (int j = 0; j < 8; ++j) o[j] = f2bf(W1[(size_t)(kbase + j) * HID_D + col]);
        } else {                          // W2: kk(4) x t(4) x lane(64)
            int r = i - 4096;
            int L = r & 63, t = (r >> 6) & 3, kk = r >> 8;
            int kbase = kk * 32 + (L >> 4) * 8;
            int col = t * 16 + (L & 15);
            unsigned short* o = Wb2 + (size_t)r * 8;
#pragma unroll
            for (int j = 0; j < 8; ++j) o[j] = f2bf(W2[(size_t)(kbase + j) * OUT_D + col]);
        }
    }
    if (i < E) {
        int d = dst[i];
        int pos = atomicAdd(&deg[d], 1);
        if (pos < CAP) srcs[(size_t)d * CAP + pos] = src[i];
    }
}

// ---- GEMM1 (MFMA): h[n,128]bf16 = rsqrt(deg+1) * (x[n,128]f32 @ W1) --------
__global__ __launch_bounds__(256) void gemm1(const float* __restrict__ x,
                                             const unsigned short* __restrict__ Wb,
                                             const int* __restrict__ deg,
                                             unsigned short* __restrict__ h, int n) {
    __shared__ __align__(16) unsigned short Ws[4 * 8 * 64 * 8];   // 32 KB
    {
        const uint4* g = (const uint4*)Wb;
        uint4* l = (uint4*)Ws;
        for (int i = threadIdx.x; i < 2048; i += 256) l[i] = g[i];
    }
    const int wave = threadIdx.x >> 6, lane = threadIdx.x & 63;
    const int wrow0 = blockIdx.x * 64 + wave * 16;
    const int mrow = min(wrow0 + (lane & 15), n - 1);
    const float* xr = x + (size_t)mrow * IN_D + ((lane >> 4) * 8);

    BF8 af[4];
#pragma unroll
    for (int kk = 0; kk < 4; ++kk) {
        float4 p  = *(const float4*)(xr + kk * 32);
        float4 q2 = *(const float4*)(xr + kk * 32 + 4);
        af[kk].u[0] = f2bf(p.x);  af[kk].u[1] = f2bf(p.y);
        af[kk].u[2] = f2bf(p.z);  af[kk].u[3] = f2bf(p.w);
        af[kk].u[4] = f2bf(q2.x); af[kk].u[5] = f2bf(q2.y);
        af[kk].u[6] = f2bf(q2.z); af[kk].u[7] = f2bf(q2.w);
    }
    __syncthreads();

    f32x4 acc[8];
#pragma unroll
    for (int t = 0; t < 8; ++t) acc[t] = (f32x4){0.f, 0.f, 0.f, 0.f};
    const bf8_t* B = (const bf8_t*)Ws;
#pragma unroll
    for (int kk = 0; kk < 4; ++kk) {
#pragma unroll
        for (int t = 0; t < 8; ++t) {
            bf8_t b = B[(kk * 8 + t) * 64 + lane];
            acc[t] = __builtin_amdgcn_mfma_f32_16x16x32_bf16(af[kk].v, b, acc[t], 0, 0, 0);
        }
    }
    const int q = lane >> 4, cbase = lane & 15;
    int rr[4]; float di[4];
#pragma unroll
    for (int r = 0; r < 4; ++r) {
        rr[r] = wrow0 + q * 4 + r;
        di[r] = rsqrtf((float)(deg[min(rr[r], n - 1)] + 1));
    }
#pragma unroll
    for (int t = 0; t < 8; ++t) {
        int col = t * 16 + cbase;
#pragma unroll
        for (int r = 0; r < 4; ++r)
            if (rr[r] < n) h[(size_t)rr[r] * HID_D + col] = f2bf(acc[t][r] * di[r]);
    }
}

// ---- FUSED layer-1 aggregate + layer-2 GEMM --------------------------------
// Phase A: gather 64 nodes (16 lanes/node, 4 passes) -> relu(bias(dinv*sum))
//          -> bf16 tile in LDS (row stride 136 ushorts)
// Phase B: MFMA the 64x128 LDS tile against W2 read DIRECT FROM GLOBAL (L2-hot,
//          16 KB) -- no W2 LDS stage, so LDS = 17 KB.
//
// R1 lesson: forcing (256,8) with the 8-deep batch (v[8]=32 VGPRs live) made
// the allocator spill to scratch (WRITE_SIZE 12.5->155 MB, dur 42->108us).
// Fix: depth-4 batch -> live set ~45-50 VGPRs, genuinely fits the 64-VGPR
// budget. MLP product preserved: depth4 x 8 waves/SIMD == depth8 x 4 waves.
#define AGG_STRIDE 136
__global__ __launch_bounds__(256, 8) void agg_gemm2(
    const unsigned short* __restrict__ hp, const int* __restrict__ srcs,
    const int* __restrict__ deg, const float* __restrict__ b1,
    const unsigned short* __restrict__ Wb2,
    unsigned short* __restrict__ g2, int n)
{
    __shared__ __align__(16) unsigned short aggs[64 * AGG_STRIDE]; // 17 KB
    const int tid = threadIdx.x;
    const int base = blockIdx.x * 64;
    const int m = tid & 15;

    // ---- phase A: gather (depth-4 batches) ----
#pragma unroll 1
    for (int pass = 0; pass < 4; ++pass) {
        int nl   = pass * 16 + (tid >> 4);
        int node = min(base + nl, n - 1);
        int dv    = deg[node];
        int k     = min(dv, CAP);
        int start = node * CAP;
        const uint4* tab = (const uint4*)hp + m;    // row stride = 16 uint4

        uint4 u = tab[(size_t)node * 16];           // self-loop term
        float a[8] = {0, 0, 0, 0, 0, 0, 0, 0};
        acc8(a, u);
#pragma unroll 1
        for (int j0 = 0; j0 < k; j0 += 4) {
            int is[4];
#pragma unroll
            for (int t = 0; t < 4; ++t) is[t] = srcs[start + min(j0 + t, k - 1)];
            uint4 v[4];
#pragma unroll
            for (int t = 0; t < 4; ++t) v[t] = tab[(size_t)is[t] * 16];
#pragma unroll
            for (int t = 0; t < 4; ++t)
                accm8(a, v[t], (j0 + t < k) ? 1.0f : 0.0f);
        }
        float di = rsqrtf((float)(dv + 1));
        const float* bb = b1 + m * 8;
        uint4 w;
        float o0, o1;
        o0 = fmaxf(a[0] * di + bb[0], 0.f);
        o1 = fmaxf(a[1] * di + bb[1], 0.f);
        w.x = (unsigned int)f2bf(o0) | ((unsigned int)f2bf(o1) << 16);
        o0 = fmaxf(a[2] * di + bb[2], 0.f);
        o1 = fmaxf(a[3] * di + bb[3], 0.f);
        w.y = (unsigned int)f2bf(o0) | ((unsigned int)f2bf(o1) << 16);
        o0 = fmaxf(a[4] * di + bb[4], 0.f);
        o1 = fmaxf(a[5] * di + bb[5], 0.f);
        w.z = (unsigned int)f2bf(o0) | ((unsigned int)f2bf(o1) << 16);
        o0 = fmaxf(a[6] * di + bb[6], 0.f);
        o1 = fmaxf(a[7] * di + bb[7], 0.f);
        w.w = (unsigned int)f2bf(o0) | ((unsigned int)f2bf(o1) << 16);
        *(uint4*)&aggs[nl * AGG_STRIDE + m * 8] = w;
    }
    __syncthreads();

    // ---- phase B: MFMA 64x128 tile @ W2 (B-frags from global/L2) -> 64x64 ---
    const int wave = tid >> 6, lane = tid & 63;
    const int qd = lane >> 4;
    const int arow = wave * 16 + (lane & 15);

    f32x4 acc[4];
#pragma unroll
    for (int t = 0; t < 4; ++t) acc[t] = (f32x4){0.f, 0.f, 0.f, 0.f};
    const bf8_t* B = (const bf8_t*)Wb2;
#pragma unroll
    for (int kk = 0; kk < 4; ++kk) {
        // per-kk A-fragment load (4 VGPRs live) keeps peak pressure low
        BF8 afk;
        afk.q = *(const uint4*)&aggs[arow * AGG_STRIDE + kk * 32 + qd * 8];
#pragma unroll
        for (int t = 0; t < 4; ++t) {
            bf8_t b = B[(kk * 4 + t) * 64 + lane];
            acc[t] = __builtin_amdgcn_mfma_f32_16x16x32_bf16(afk.v, b, acc[t], 0, 0, 0);
        }
    }
    const int cbase = lane & 15;
    int rr[4]; float di[4];
#pragma unroll
    for (int r = 0; r < 4; ++r) {
        rr[r] = base + wave * 16 + qd * 4 + r;
        di[r] = rsqrtf((float)(deg[min(rr[r], n - 1)] + 1));
    }
#pragma unroll
    for (int t = 0; t < 4; ++t) {
        int col = t * 16 + cbase;
#pragma unroll
        for (int r = 0; r < 4; ++r)
            if (rr[r] < n) g2[(size_t)rr[r] * OUT_D + col] = f2bf(acc[t][r] * di[r]);
    }
}

// ---- gather layer 2: 8 nodes/wave (8 lanes each), depth-4 load batches -----
// Same latency-bound profile as agg_gemm2 phase A -> same depth-4 + (256,8).
__global__ __launch_bounds__(256, 8) void gather64(const unsigned short* __restrict__ gp,
                                                   const int* __restrict__ srcs,
                                                   const int* __restrict__ deg,
                                                   const float* __restrict__ b,
                                                   float* __restrict__ out, int n) {
    int idx  = blockIdx.x * 256 + threadIdx.x;
    int node = idx >> 3;            // one node per 8-lane group
    int m    = idx & 7;             // 16B chunk index within 128B row
    if (node >= n) return;
    int dv    = deg[node];
    int k     = min(dv, CAP);
    int start = node * CAP;
    const uint4* tab = (const uint4*)gp + m;    // row stride = 8 uint4

    uint4 u = tab[(size_t)node * 8];            // self-loop term
    float a[8] = {0, 0, 0, 0, 0, 0, 0, 0};
    acc8(a, u);
#pragma unroll 1
    for (int j0 = 0; j0 < k; j0 += 4) {
        int is[4];
#pragma unroll
        for (int t = 0; t < 4; ++t) is[t] = srcs[start + min(j0 + t, k - 1)];
        uint4 v[4];
#pragma unroll
        for (int t = 0; t < 4; ++t) v[t] = tab[(size_t)is[t] * 8];
#pragma unroll
        for (int t = 0; t < 4; ++t)
            accm8(a, v[t], (j0 + t < k) ? 1.0f : 0.0f);
    }
    float di = rsqrtf((float)(dv + 1));
    const float* bb = b + m * 8;
    float4 w0, w1;
    w0.x = a[0] * di + bb[0];
    w0.y = a[1] * di + bb[1];
    w0.z = a[2] * di + bb[2];
    w0.w = a[3] * di + bb[3];
    w1.x = a[4] * di + bb[4];
    w1.y = a[5] * di + bb[5];
    w1.z = a[6] * di + bb[6];
    w1.w = a[7] * di + bb[7];
    float* o = out + (size_t)node * OUT_D + m * 8;
    *(float4*)o = w0;
    *(float4*)(o + 4) = w1;
}

extern "C" void kernel_launch(void* const* d_in, const int* in_sizes, int n_in,
                              void* d_out, int out_size, void* d_ws, size_t ws_size,
                              hipStream_t stream) {
    const float* x  = (const float*)d_in[0];
    const int*   ei = (const int*)d_in[1];
    const float* W1 = (const float*)d_in[2];
    const float* b1 = (const float*)d_in[3];
    const float* W2 = (const float*)d_in[4];
    const float* b2 = (const float*)d_in[5];
    float* out = (float*)d_out;

    const int n = in_sizes[0] / IN_D;   // 100000
    const int E = in_sizes[1] / 2;      // 600000
    const int* src = ei;
    const int* dst = ei + E;

    // workspace layout (~52 MB)
    char* ws = (char*)d_ws;
    size_t off = 0;
    int* deg  = (int*)(ws + off); off += align256((size_t)n * sizeof(int));
    int* srcs = (int*)(ws + off); off += align256((size_t)n * CAP * sizeof(int));
    unsigned short* Wb1 = (unsigned short*)(ws + off); off += align256(4096 * 8 * sizeof(unsigned short));
    unsigned short* Wb2 = (unsigned short*)(ws + off); off += align256(2048 * 8 * sizeof(unsigned short));
    unsigned short* h1  = (unsigned short*)(ws + off); off += align256((size_t)n * HID_D * sizeof(unsigned short));
    unsigned short* g2  = (unsigned short*)(ws + off); off += align256((size_t)n * OUT_D * sizeof(unsigned short));

    // 1) zero degree counters
    hipMemsetAsync(deg, 0, (size_t)n * sizeof(int), stream);
    // 2) bucket-CSR placement + weight pre-swizzle
    place_prep<<<(E + 255) / 256, 256, 0, stream>>>(src, dst, deg, srcs,
                                                    W1, W2, Wb1, Wb2, E);
    // 3) layer 1 transform
    gemm1<<<(n + 63) / 64, 256, 0, stream>>>(x, Wb1, deg, h1, n);
    // 4) fused layer-1 aggregate + layer-2 transform
    agg_gemm2<<<(n + 63) / 64, 256, 0, stream>>>(h1, srcs, deg, b1, Wb2, g2, n);
    // 5) layer 2 aggregate + bias -> out (fp32)
    gather64<<<(n + 31) / 32, 256, 0, stream>>>(g2, srcs, deg, b2, out, n);
}